// Round 7
// baseline (568.174 us; speedup 1.0000x reference)
//
#include <hip/hip_runtime.h>
#include <hip/hip_bf16.h>
#include <math.h>

#define TSTEPS 60
#define DIN 6

typedef __attribute__((ext_vector_type(8))) short short8v;
typedef __attribute__((ext_vector_type(4))) float f32x4;
#define MFMA16 __builtin_amdgcn_mfma_f32_16x16x32_bf16

__device__ __forceinline__ float fast_rcp(float x) { return __builtin_amdgcn_rcpf(x); }
__device__ __forceinline__ float sigf(float x) { return fast_rcp(1.0f + __expf(-x)); }
__device__ __forceinline__ float tanhf_(float x) {
    return 1.0f - 2.0f * fast_rcp(__expf(2.0f * x) + 1.0f);
}
__device__ __forceinline__ unsigned short f2bf(float f) {   // RTN-even
    unsigned u = __float_as_uint(f);
    u += 0x7fff + ((u >> 16) & 1);
    return (unsigned short)(u >> 16);
}
__device__ __forceinline__ float bf2f(unsigned short s) {
    return __uint_as_float(((unsigned)s) << 16);
}
// load 8 consecutive fp32 -> split-bf16 hi/lo frags
__device__ __forceinline__ void ld_split(const float* p, short8v& hi, short8v& lo) {
    float4 a = *(const float4*)p, b = *(const float4*)(p + 4);
    float v[8] = {a.x, a.y, a.z, a.w, b.x, b.y, b.z, b.w};
    short h8[8], l8[8];
#pragma unroll
    for (int e = 0; e < 8; ++e) {
        unsigned short h = f2bf(v[e]);
        h8[e] = (short)h; l8[e] = (short)f2bf(v[e] - bf2f(h));
    }
    hi = *(short8v*)h8; lo = *(short8v*)l8;
}

// ---------------------------------------------------------------------------
// K1: fused 2-layer GRU, 60 steps, MFMA split-bf16 (hi+lo, 3-term) matmuls.
// ALL weight B-frags live in REGISTERS (36 frags = 144 VGPR), staged once
// from global (lane-contiguous 8-float row slices). LDS is only the 4 h
// planes (16 KB). Per-step LDS: 12 ds_read_b128 + 16 ds_write_b16
// (was 36 reads -> LDS-pipe-bound). 256 blocks x 512 thr, 2 waves/SIMD.
// ---------------------------------------------------------------------------
__global__ __launch_bounds__(512, 2)
void gru_fused(const float* __restrict__ x,
               const float* __restrict__ Wih0, const float* __restrict__ Whh0,
               const float* __restrict__ bih0, const float* __restrict__ bhh0,
               const float* __restrict__ Wih1, const float* __restrict__ Whh1,
               const float* __restrict__ bih1, const float* __restrict__ bhh1,
               float* __restrict__ hidden)
{
    __shared__ char ldsb[16384];   // h0_hi | h0_lo | h1_hi | h1_lo, 4 KB each

    const int tid = threadIdx.x;
    const int l   = tid & 63;
    const int w   = tid >> 6;
    const int mt  = w >> 2;          // m-tile 0..1 (rows)
    const int ur  = w & 3;           // unit-range 0..3
    const int l15 = l & 15;
    const int kb  = l >> 4;
    const int u_m = ur * 16 + l15;   // my unit column
    const int n0  = blockIdx.x * 32;

    for (int i = tid; i < 4096; i += 512) *(unsigned*)(ldsb + i * 4) = 0u;

    // ---- weight fragments -> registers (one-time) ----
    short8v W0h[3][2], W0l[3][2];    // Whh0  [gate][kt]
    short8v V1h[3][2], V1l[3][2];    // Wih1
    short8v U1h[3][2], U1l[3][2];    // Whh1
#pragma unroll
    for (int g = 0; g < 3; ++g)
#pragma unroll
        for (int kt = 0; kt < 2; ++kt) {
            int off = (g * 64 + u_m) * 64 + kt * 32 + kb * 8;
            ld_split(Whh0 + off, W0h[g][kt], W0l[g][kt]);
            ld_split(Wih1 + off, V1h[g][kt], V1l[g][kt]);
            ld_split(Whh1 + off, U1h[g][kt], U1l[g][kt]);
        }

    float brz0_r = bih0[u_m] + bhh0[u_m];
    float brz0_z = bih0[64 + u_m] + bhh0[64 + u_m];
    float bi0n = bih0[128 + u_m], bh0n = bhh0[128 + u_m];
    float brz1_r = bih1[u_m] + bhh1[u_m];
    float brz1_z = bih1[64 + u_m] + bhh1[64 + u_m];
    float bi1n = bih1[128 + u_m], bh1n = bhh1[128 + u_m];

    float Wx[3][DIN];
#pragma unroll
    for (int g = 0; g < 3; ++g)
#pragma unroll
        for (int d = 0; d < DIN; ++d) Wx[g][d] = Wih0[(g * 64 + u_m) * DIN + d];

    const int rowA = mt * 16 + l15;
    const int bA0 = rowA * 128 + ((kb ^ (rowA & 7)) << 4);
    const int bA1 = bA0 ^ 64;
    int wAo[4];
#pragma unroll
    for (int i = 0; i < 4; ++i) {
        int r = mt * 16 + kb * 4 + i;
        wAo[i] = r * 128 + (((u_m >> 3) ^ (r & 7)) << 4) + (u_m & 7) * 2;
    }
    const float* xp[4];
#pragma unroll
    for (int i = 0; i < 4; ++i)
        xp[i] = x + (size_t)(n0 + mt * 16 + kb * 4 + i) * (DIN * TSTEPS);

    float h0f[4] = {0.f, 0.f, 0.f, 0.f};
    float h1f[4] = {0.f, 0.f, 0.f, 0.f};

    __syncthreads();

#define LD8(o) (*(const short8v*)(ldsb + (o)))

#pragma unroll 1
    for (int t = 0; t < TSTEPS; ++t) {
        // A-frags of h0(old):  [kt][hi/lo]
        short8v aH0[2][2];
        aH0[0][0] = LD8(bA0);        aH0[1][0] = LD8(bA1);
        aH0[0][1] = LD8(bA0 + 4096); aH0[1][1] = LD8(bA1 + 4096);

        // accumulators init with bias + x-part
        f32x4 Cr, Cz, Cnh;
#pragma unroll
        for (int i = 0; i < 4; ++i) {
            float s0 = brz0_r, s1 = brz0_z, s2 = 0.f;
#pragma unroll
            for (int d = 0; d < DIN; ++d) {
                float xd = xp[i][d * TSTEPS + t];
                s0 = fmaf(Wx[0][d], xd, s0);
                s1 = fmaf(Wx[1][d], xd, s1);
                s2 = fmaf(Wx[2][d], xd, s2);
            }
            Cr[i] = s0; Cz[i] = s1; Cnh[i] = s2;   // Cnh holds gi_n for now
        }
        // stash gi_n, run hh-part of n in Cnh
        float gin[4];
#pragma unroll
        for (int i = 0; i < 4; ++i) { gin[i] = Cnh[i]; Cnh[i] = bh0n; }

        Cr = MFMA16(aH0[0][0], W0h[0][0], Cr, 0, 0, 0);
        Cr = MFMA16(aH0[1][0], W0h[0][1], Cr, 0, 0, 0);
        Cr = MFMA16(aH0[0][1], W0h[0][0], Cr, 0, 0, 0);
        Cr = MFMA16(aH0[1][1], W0h[0][1], Cr, 0, 0, 0);
        Cr = MFMA16(aH0[0][0], W0l[0][0], Cr, 0, 0, 0);
        Cr = MFMA16(aH0[1][0], W0l[0][1], Cr, 0, 0, 0);
        Cz = MFMA16(aH0[0][0], W0h[1][0], Cz, 0, 0, 0);
        Cz = MFMA16(aH0[1][0], W0h[1][1], Cz, 0, 0, 0);
        Cz = MFMA16(aH0[0][1], W0h[1][0], Cz, 0, 0, 0);
        Cz = MFMA16(aH0[1][1], W0h[1][1], Cz, 0, 0, 0);
        Cz = MFMA16(aH0[0][0], W0l[1][0], Cz, 0, 0, 0);
        Cz = MFMA16(aH0[1][0], W0l[1][1], Cz, 0, 0, 0);
        Cnh = MFMA16(aH0[0][0], W0h[2][0], Cnh, 0, 0, 0);
        Cnh = MFMA16(aH0[1][0], W0h[2][1], Cnh, 0, 0, 0);
        Cnh = MFMA16(aH0[0][1], W0h[2][0], Cnh, 0, 0, 0);
        Cnh = MFMA16(aH0[1][1], W0h[2][1], Cnh, 0, 0, 0);
        Cnh = MFMA16(aH0[0][0], W0l[2][0], Cnh, 0, 0, 0);
        Cnh = MFMA16(aH0[1][0], W0l[2][1], Cnh, 0, 0, 0);

        unsigned short hh[4], hl[4];
#pragma unroll
        for (int i = 0; i < 4; ++i) {
            float r = sigf(Cr[i]);
            float z = sigf(Cz[i]);
            float n = tanhf_(gin[i] + bi0n + r * Cnh[i]);
            h0f[i] = (1.f - z) * n + z * h0f[i];
            hh[i] = f2bf(h0f[i]);
            hl[i] = f2bf(h0f[i] - bf2f(hh[i]));
        }
        __syncthreads();   // B1: all h0 A-reads done
#pragma unroll
        for (int i = 0; i < 4; ++i) {
            *(unsigned short*)(ldsb + wAo[i]) = hh[i];
            *(unsigned short*)(ldsb + wAo[i] + 4096) = hl[i];
        }
        // read h1(old) here: h1 planes are written only after B2 (safe zone)
        short8v aH1[2][2];
        aH1[0][0] = LD8(bA0 + 8192);  aH1[1][0] = LD8(bA1 + 8192);
        aH1[0][1] = LD8(bA0 + 12288); aH1[1][1] = LD8(bA1 + 12288);
        __syncthreads();   // B2: h0' visible

        // ===== layer 1 =====
        short8v aN[2][2];
        aN[0][0] = LD8(bA0);        aN[1][0] = LD8(bA1);
        aN[0][1] = LD8(bA0 + 4096); aN[1][1] = LD8(bA1 + 4096);

        f32x4 Dr, Dz, Dni, Dnh;
#pragma unroll
        for (int i = 0; i < 4; ++i) {
            Dr[i] = brz1_r; Dz[i] = brz1_z; Dni[i] = bi1n; Dnh[i] = bh1n;
        }
        Dr = MFMA16(aN[0][0], V1h[0][0], Dr, 0, 0, 0);
        Dr = MFMA16(aN[1][0], V1h[0][1], Dr, 0, 0, 0);
        Dr = MFMA16(aN[0][1], V1h[0][0], Dr, 0, 0, 0);
        Dr = MFMA16(aN[1][1], V1h[0][1], Dr, 0, 0, 0);
        Dr = MFMA16(aN[0][0], V1l[0][0], Dr, 0, 0, 0);
        Dr = MFMA16(aN[1][0], V1l[0][1], Dr, 0, 0, 0);
        Dr = MFMA16(aH1[0][0], U1h[0][0], Dr, 0, 0, 0);
        Dr = MFMA16(aH1[1][0], U1h[0][1], Dr, 0, 0, 0);
        Dr = MFMA16(aH1[0][1], U1h[0][0], Dr, 0, 0, 0);
        Dr = MFMA16(aH1[1][1], U1h[0][1], Dr, 0, 0, 0);
        Dr = MFMA16(aH1[0][0], U1l[0][0], Dr, 0, 0, 0);
        Dr = MFMA16(aH1[1][0], U1l[0][1], Dr, 0, 0, 0);

        Dz = MFMA16(aN[0][0], V1h[1][0], Dz, 0, 0, 0);
        Dz = MFMA16(aN[1][0], V1h[1][1], Dz, 0, 0, 0);
        Dz = MFMA16(aN[0][1], V1h[1][0], Dz, 0, 0, 0);
        Dz = MFMA16(aN[1][1], V1h[1][1], Dz, 0, 0, 0);
        Dz = MFMA16(aN[0][0], V1l[1][0], Dz, 0, 0, 0);
        Dz = MFMA16(aN[1][0], V1l[1][1], Dz, 0, 0, 0);
        Dz = MFMA16(aH1[0][0], U1h[1][0], Dz, 0, 0, 0);
        Dz = MFMA16(aH1[1][0], U1h[1][1], Dz, 0, 0, 0);
        Dz = MFMA16(aH1[0][1], U1h[1][0], Dz, 0, 0, 0);
        Dz = MFMA16(aH1[1][1], U1h[1][1], Dz, 0, 0, 0);
        Dz = MFMA16(aH1[0][0], U1l[1][0], Dz, 0, 0, 0);
        Dz = MFMA16(aH1[1][0], U1l[1][1], Dz, 0, 0, 0);

        Dni = MFMA16(aN[0][0], V1h[2][0], Dni, 0, 0, 0);
        Dni = MFMA16(aN[1][0], V1h[2][1], Dni, 0, 0, 0);
        Dni = MFMA16(aN[0][1], V1h[2][0], Dni, 0, 0, 0);
        Dni = MFMA16(aN[1][1], V1h[2][1], Dni, 0, 0, 0);
        Dni = MFMA16(aN[0][0], V1l[2][0], Dni, 0, 0, 0);
        Dni = MFMA16(aN[1][0], V1l[2][1], Dni, 0, 0, 0);
        Dnh = MFMA16(aH1[0][0], U1h[2][0], Dnh, 0, 0, 0);
        Dnh = MFMA16(aH1[1][0], U1h[2][1], Dnh, 0, 0, 0);
        Dnh = MFMA16(aH1[0][1], U1h[2][0], Dnh, 0, 0, 0);
        Dnh = MFMA16(aH1[1][1], U1h[2][1], Dnh, 0, 0, 0);
        Dnh = MFMA16(aH1[0][0], U1l[2][0], Dnh, 0, 0, 0);
        Dnh = MFMA16(aH1[1][0], U1l[2][1], Dnh, 0, 0, 0);

#pragma unroll
        for (int i = 0; i < 4; ++i) {
            float r = sigf(Dr[i]);
            float z = sigf(Dz[i]);
            float n = tanhf_(Dni[i] + r * Dnh[i]);
            h1f[i] = (1.f - z) * n + z * h1f[i];
            unsigned short hhi = f2bf(h1f[i]);
            *(unsigned short*)(ldsb + wAo[i] + 8192) = hhi;
            *(unsigned short*)(ldsb + wAo[i] + 12288) = f2bf(h1f[i] - bf2f(hhi));
        }
        __syncthreads();   // B3: h1' visible; next step safe
    }

#pragma unroll
    for (int i = 0; i < 4; ++i)
        hidden[(size_t)(n0 + mt * 16 + kb * 4 + i) * 64 + u_m] = h1f[i];
#undef LD8
}

// ---------------------------------------------------------------------------
// K2: t = hidden @ tW.T + tb ; s1 = t@a1 ; s2 = t@a2 ; + exp branch tables.
// Coalesced tW read + padded-LDS transposed store (no bank conflicts).
// ---------------------------------------------------------------------------
__global__ __launch_bounds__(256)
void attn_prep(const float* __restrict__ hidden, const float* __restrict__ tW,
               const float* __restrict__ tb, const float* __restrict__ a,
               float* __restrict__ s1, float* __restrict__ s2,
               float* __restrict__ E1p, float* __restrict__ E1n,
               float* __restrict__ E2p, float* __restrict__ E2n)
{
    __shared__ float WT[64 * 65];
    __shared__ float hrow[4][64];
    int tid = threadIdx.x, c = tid & 63, rw = tid >> 6;
    for (int i = tid; i < 4096; i += 256) {
        int cc = i >> 6, u = i & 63;          // tW[cc][u], coalesced read
        WT[u * 65 + cc] = tW[i];
    }
    int row = blockIdx.x * 4 + rw;
    hrow[rw][c] = hidden[(size_t)row * 64 + c];
    __syncthreads();
    float tc = tb[c];
    for (int u = 0; u < 64; ++u) tc += WT[u * 65 + c] * hrow[rw][u];
    float p1 = tc * a[c], p2 = tc * a[64 + c];
#pragma unroll
    for (int o = 32; o; o >>= 1) { p1 += __shfl_xor(p1, o); p2 += __shfl_xor(p2, o); }
    if (c == 0) {
        s1[row] = p1; s2[row] = p2;
        E1p[row] = expf(p1); E1n[row] = expf(0.01f * p1);
        E2p[row] = expf(p2); E2n[row] = expf(0.01f * p2);
    }
}

// ---------------------------------------------------------------------------
// K3: frag-native transposed planes: hiTf[j>>3][c][8] (hi and lo), so a
// flash_attn B-frag wave-load is 256B-contiguous per 16-lane group.
// ---------------------------------------------------------------------------
__global__ __launch_bounds__(256)
void transposeHbf(const float* __restrict__ hidden,
                  unsigned short* __restrict__ hiTh, unsigned short* __restrict__ hiTl)
{
    __shared__ float tile[64][65];
    int b = blockIdx.x, tid = threadIdx.x;
    for (int i = tid; i < 4096; i += 256) {
        int r = i >> 6, c = i & 63;
        tile[c][r] = hidden[(size_t)(b * 64 + r) * 64 + c];
    }
    __syncthreads();
    int c = tid & 63, seg = tid >> 6;      // 16 j's per (c,seg)
    unsigned short oh[16], ol[16];
#pragma unroll
    for (int k = 0; k < 16; ++k) {
        float v = tile[c][seg * 16 + k];
        unsigned short h = f2bf(v);
        oh[k] = h; ol[k] = f2bf(v - bf2f(h));
    }
    int jb = b * 8 + seg * 2;              // j>>3 of first 8-chunk
    size_t b0 = ((size_t)jb * 64 + c) * 8;
    size_t b1 = ((size_t)(jb + 1) * 64 + c) * 8;
    *(short8v*)(hiTh + b0) = *(const short8v*)(oh);
    *(short8v*)(hiTh + b1) = *(const short8v*)(oh + 8);
    *(short8v*)(hiTl + b0) = *(const short8v*)(ol);
    *(short8v*)(hiTl + b1) = *(const short8v*)(ol + 8);
}

// ---------------------------------------------------------------------------
// K4: flash attention via rank-1 branch decomposition (no per-pair exp).
// 512 blocks x 4 waves; block = 16 att-rows, wave = j-quarter (2048 j's,
// 64 iters). B-frags from frag-native planes (coalesced). 2 waves/SIMD.
// ---------------------------------------------------------------------------
__global__ __launch_bounds__(256)
void flash_attn(const float* __restrict__ s1, const float* __restrict__ s2,
                const float* __restrict__ E1p, const float* __restrict__ E1n,
                const float* __restrict__ E2p, const float* __restrict__ E2n,
                const unsigned short* __restrict__ hiTh,
                const unsigned short* __restrict__ hiTl,
                const float* __restrict__ hidden, float* __restrict__ h2)
{
    __shared__ float comb[4][64][17];
    const int tid = threadIdx.x;
    const int l = tid & 63, w = tid >> 6;     // w = j-quarter
    const int l15 = l & 15, kb = l >> 4;
    const int i0 = blockIdx.x * 16;

    const float s2i  = s2[i0 + l15];
    const float E2pv = E2p[i0 + l15];
    const float E2nv = E2n[i0 + l15];

    f32x4 C[4];
#pragma unroll
    for (int ct = 0; ct < 4; ++ct)
#pragma unroll
        for (int r = 0; r < 4; ++r) C[ct][r] = 0.f;
    float den = 0.f;

#pragma unroll 2
    for (int it = 0; it < 64; ++it) {
        const int jk = w * 2048 + it * 32 + kb * 8;
        const int jb = w * 256 + it * 4 + kb;          // j>>3
        float4 s1a = *(const float4*)(s1 + jk);
        float4 s1b = *(const float4*)(s1 + jk + 4);
        float4 p1a = *(const float4*)(E1p + jk);
        float4 p1b = *(const float4*)(E1p + jk + 4);
        float4 n1a = *(const float4*)(E1n + jk);
        float4 n1b = *(const float4*)(E1n + jk + 4);

        short8v Bh[4], Bl[4];
#pragma unroll
        for (int ct = 0; ct < 4; ++ct) {
            size_t off = ((size_t)jb * 64 + ct * 16 + l15) * 8;
            Bh[ct] = *(const short8v*)(hiTh + off);
            Bl[ct] = *(const short8v*)(hiTl + off);
        }

        unsigned short ah[8], al[8];
#define MK(e, sv, pv, nv)                                            \
        {                                                            \
            float s = s2i + (sv);                                    \
            bool cpos = s > 0.f;                                     \
            float w1 = cpos ? (pv) : (nv);                           \
            float w2 = cpos ? E2pv : E2nv;                           \
            float ev = w1 * w2;                                      \
            den += ev;                                               \
            unsigned short hx = f2bf(ev);                            \
            ah[e] = hx; al[e] = f2bf(ev - bf2f(hx));                 \
        }
        MK(0, s1a.x, p1a.x, n1a.x) MK(1, s1a.y, p1a.y, n1a.y)
        MK(2, s1a.z, p1a.z, n1a.z) MK(3, s1a.w, p1a.w, n1a.w)
        MK(4, s1b.x, p1b.x, n1b.x) MK(5, s1b.y, p1b.y, n1b.y)
        MK(6, s1b.z, p1b.z, n1b.z) MK(7, s1b.w, p1b.w, n1b.w)
#undef MK
        short8v Ah = { (short)ah[0], (short)ah[1], (short)ah[2], (short)ah[3],
                       (short)ah[4], (short)ah[5], (short)ah[6], (short)ah[7] };
        short8v Al = { (short)al[0], (short)al[1], (short)al[2], (short)al[3],
                       (short)al[4], (short)al[5], (short)al[6], (short)al[7] };

#pragma unroll
        for (int ct = 0; ct < 4; ++ct) {
            C[ct] = MFMA16(Ah, Bh[ct], C[ct], 0, 0, 0);
            C[ct] = MFMA16(Al, Bh[ct], C[ct], 0, 0, 0);
            C[ct] = MFMA16(Ah, Bl[ct], C[ct], 0, 0, 0);
        }
    }

    den += __shfl_xor(den, 16);
    den += __shfl_xor(den, 32);

#pragma unroll
    for (int ct = 0; ct < 4; ++ct)
#pragma unroll
        for (int r = 0; r < 4; ++r) comb[w][l][ct * 4 + r] = C[ct][r];
    comb[w][l][16] = den;
    __syncthreads();

    if (w == 0) {
        float den_t = comb[0][l][16] + comb[1][l][16] + comb[2][l][16] + comb[3][l][16];
#pragma unroll
        for (int ct = 0; ct < 4; ++ct) {
#pragma unroll
            for (int r = 0; r < 4; ++r) {
                int rr = kb * 4 + r;
                float num = comb[0][l][ct * 4 + r] + comb[1][l][ct * 4 + r]
                          + comb[2][l][ct * 4 + r] + comb[3][l][ct * 4 + r];
                float dv = __shfl(den_t, rr);
                size_t oidx = (size_t)(i0 + rr) * 64 + ct * 16 + l15;
                h2[oidx] = num / dv + hidden[oidx];
            }
        }
    }
}

// ---------------------------------------------------------------------------
// K5: h = leaky(h2 @ fcW.T + fcb) ; out = h @ outW.T + outb.  4 rows/block.
// ---------------------------------------------------------------------------
__global__ __launch_bounds__(256)
void fc_out(const float* __restrict__ h2,
            const float* __restrict__ fcW, const float* __restrict__ fcb,
            const float* __restrict__ outW, const float* __restrict__ outb,
            float* __restrict__ out)
{
    __shared__ float fcWT[64 * 65];
    __shared__ float hrow[4][64];
    int tid = threadIdx.x, c = tid & 63, rw = tid >> 6;
    for (int i = tid; i < 4096; i += 256) {
        int cc = i >> 6, u = i & 63;
        fcWT[u * 65 + cc] = fcW[i];
    }
    int row = blockIdx.x * 4 + rw;
    hrow[rw][c] = h2[(size_t)row * 64 + c];
    __syncthreads();
    float y = fcb[c];
    for (int u = 0; u < 64; ++u) y += fcWT[u * 65 + c] * hrow[rw][u];
    y = y > 0.f ? y : 0.01f * y;
    float o = y * outW[c];
#pragma unroll
    for (int s = 32; s; s >>= 1) o += __shfl_xor(o, s);
    if (c == 0) out[row] = o + outb[0];
}

extern "C" void kernel_launch(void* const* d_in, const int* in_sizes, int n_in,
                              void* d_out, int out_size, void* d_ws, size_t ws_size,
                              hipStream_t stream)
{
    const float* x     = (const float*)d_in[0];
    const float* Wih0  = (const float*)d_in[1];
    const float* Whh0  = (const float*)d_in[2];
    const float* bih0  = (const float*)d_in[3];
    const float* bhh0  = (const float*)d_in[4];
    const float* Wih1  = (const float*)d_in[5];
    const float* Whh1  = (const float*)d_in[6];
    const float* bih1  = (const float*)d_in[7];
    const float* bhh1  = (const float*)d_in[8];
    const float* tW    = (const float*)d_in[9];
    const float* tb    = (const float*)d_in[10];
    const float* a     = (const float*)d_in[11];
    const float* fcW   = (const float*)d_in[12];
    const float* fcb   = (const float*)d_in[13];
    const float* outW  = (const float*)d_in[14];
    const float* outb  = (const float*)d_in[15];

    float* ws      = (float*)d_ws;
    float* hidden  = ws;                          // 8192*64        (524288)
    float* s1      = hidden + 524288;             // 8192
    float* s2      = s1 + 8192;
    float* E1p     = s2 + 8192;
    float* E1n     = E1p + 8192;
    float* E2p     = E1n + 8192;
    float* E2n     = E2p + 8192;                  // ends at 573440 floats
    unsigned short* hiTh = (unsigned short*)(ws + 573440);   // 8192*64 u16
    unsigned short* hiTl = hiTh + 524288;                    // 8192*64 u16
    float* h2      = ws + 573440 + 524288;        // 8192*64 f32

    gru_fused<<<256, 512, 0, stream>>>(x, Wih0, Whh0, bih0, bhh0,
                                       Wih1, Whh1, bih1, bhh1, hidden);
    attn_prep<<<2048, 256, 0, stream>>>(hidden, tW, tb, a, s1, s2,
                                        E1p, E1n, E2p, E2n);
    transposeHbf<<<128, 256, 0, stream>>>(hidden, hiTh, hiTl);
    flash_attn<<<512, 256, 0, stream>>>(s1, s2, E1p, E1n, E2p, E2n,
                                        hiTh, hiTl, hidden, h2);
    fc_out<<<2048, 256, 0, stream>>>(h2, fcW, fcb, outW, outb, (float*)d_out);
}

// Round 9
// 484.118 us; speedup vs baseline: 1.1736x; 1.1736x over previous
//
#include <hip/hip_runtime.h>
#include <hip/hip_bf16.h>
#include <math.h>

#define TSTEPS 60
#define DIN 6

typedef __attribute__((ext_vector_type(8))) short short8v;
typedef __attribute__((ext_vector_type(4))) float f32x4;
#define MFMA16 __builtin_amdgcn_mfma_f32_16x16x32_bf16

__device__ __forceinline__ float fast_rcp(float x) { return __builtin_amdgcn_rcpf(x); }
__device__ __forceinline__ float sigf(float x) { return fast_rcp(1.0f + __expf(-x)); }
__device__ __forceinline__ float tanhf_(float x) {
    return 1.0f - 2.0f * fast_rcp(__expf(2.0f * x) + 1.0f);
}
__device__ __forceinline__ unsigned short f2bf(float f) {   // RTN-even
    unsigned u = __float_as_uint(f);
    u += 0x7fff + ((u >> 16) & 1);
    return (unsigned short)(u >> 16);
}
__device__ __forceinline__ float bf2f(unsigned short s) {
    return __uint_as_float(((unsigned)s) << 16);
}
// load 8 consecutive fp32 -> split-bf16 hi/lo frags
__device__ __forceinline__ void ld_split(const float* p, short8v& hi, short8v& lo) {
    float4 a = *(const float4*)p, b = *(const float4*)(p + 4);
    float v[8] = {a.x, a.y, a.z, a.w, b.x, b.y, b.z, b.w};
    short h8[8], l8[8];
#pragma unroll
    for (int e = 0; e < 8; ++e) {
        unsigned short h = f2bf(v[e]);
        h8[e] = (short)h; l8[e] = (short)f2bf(v[e] - bf2f(h));
    }
    hi = *(short8v*)h8; lo = *(short8v*)l8;
}

// ---------------------------------------------------------------------------
// K1: fused 2-layer GRU, 60 steps, MFMA split-bf16 (hi+lo, 3-term) matmuls.
// Weight B-frags in REGISTERS (36 frags = 144 VGPR). LDS = 16 KB h planes.
// __launch_bounds__(512,1): min 1 BLOCK/CU (CUDA semantics!) -> VGPR cap 256.
// Round-7's (512,2) capped VGPR at 128 -> full weight-array spill to scratch
// (FETCH 200MB, WRITE 60MB). This is the fix.
// ---------------------------------------------------------------------------
__global__ __launch_bounds__(512, 1)
void gru_fused(const float* __restrict__ x,
               const float* __restrict__ Wih0, const float* __restrict__ Whh0,
               const float* __restrict__ bih0, const float* __restrict__ bhh0,
               const float* __restrict__ Wih1, const float* __restrict__ Whh1,
               const float* __restrict__ bih1, const float* __restrict__ bhh1,
               float* __restrict__ hidden)
{
    __shared__ char ldsb[16384];   // h0_hi | h0_lo | h1_hi | h1_lo, 4 KB each

    const int tid = threadIdx.x;
    const int l   = tid & 63;
    const int w   = tid >> 6;
    const int mt  = w >> 2;          // m-tile 0..1 (rows)
    const int ur  = w & 3;           // unit-range 0..3
    const int l15 = l & 15;
    const int kb  = l >> 4;
    const int u_m = ur * 16 + l15;   // my unit column
    const int n0  = blockIdx.x * 32;

    for (int i = tid; i < 4096; i += 512) *(unsigned*)(ldsb + i * 4) = 0u;

    // ---- weight fragments -> registers (one-time) ----
    short8v W0h[3][2], W0l[3][2];    // Whh0  [gate][kt]
    short8v V1h[3][2], V1l[3][2];    // Wih1
    short8v U1h[3][2], U1l[3][2];    // Whh1
#pragma unroll
    for (int g = 0; g < 3; ++g)
#pragma unroll
        for (int kt = 0; kt < 2; ++kt) {
            int off = (g * 64 + u_m) * 64 + kt * 32 + kb * 8;
            ld_split(Whh0 + off, W0h[g][kt], W0l[g][kt]);
            ld_split(Wih1 + off, V1h[g][kt], V1l[g][kt]);
            ld_split(Whh1 + off, U1h[g][kt], U1l[g][kt]);
        }

    float brz0_r = bih0[u_m] + bhh0[u_m];
    float brz0_z = bih0[64 + u_m] + bhh0[64 + u_m];
    float bi0n = bih0[128 + u_m], bh0n = bhh0[128 + u_m];
    float brz1_r = bih1[u_m] + bhh1[u_m];
    float brz1_z = bih1[64 + u_m] + bhh1[64 + u_m];
    float bi1n = bih1[128 + u_m], bh1n = bhh1[128 + u_m];

    float Wx[3][DIN];
#pragma unroll
    for (int g = 0; g < 3; ++g)
#pragma unroll
        for (int d = 0; d < DIN; ++d) Wx[g][d] = Wih0[(g * 64 + u_m) * DIN + d];

    const int rowA = mt * 16 + l15;
    const int bA0 = rowA * 128 + ((kb ^ (rowA & 7)) << 4);
    const int bA1 = bA0 ^ 64;
    int wAo[4];
#pragma unroll
    for (int i = 0; i < 4; ++i) {
        int r = mt * 16 + kb * 4 + i;
        wAo[i] = r * 128 + (((u_m >> 3) ^ (r & 7)) << 4) + (u_m & 7) * 2;
    }
    const float* xp[4];
#pragma unroll
    for (int i = 0; i < 4; ++i)
        xp[i] = x + (size_t)(n0 + mt * 16 + kb * 4 + i) * (DIN * TSTEPS);

    float h0f[4] = {0.f, 0.f, 0.f, 0.f};
    float h1f[4] = {0.f, 0.f, 0.f, 0.f};

    __syncthreads();

#define LD8(o) (*(const short8v*)(ldsb + (o)))

#pragma unroll 1
    for (int t = 0; t < TSTEPS; ++t) {
        // A-frags of h0(old):  [kt][hi/lo]
        short8v aH0[2][2];
        aH0[0][0] = LD8(bA0);        aH0[1][0] = LD8(bA1);
        aH0[0][1] = LD8(bA0 + 4096); aH0[1][1] = LD8(bA1 + 4096);

        // accumulators init with bias + x-part
        f32x4 Cr, Cz, Cnh;
#pragma unroll
        for (int i = 0; i < 4; ++i) {
            float s0 = brz0_r, s1 = brz0_z, s2 = 0.f;
#pragma unroll
            for (int d = 0; d < DIN; ++d) {
                float xd = xp[i][d * TSTEPS + t];
                s0 = fmaf(Wx[0][d], xd, s0);
                s1 = fmaf(Wx[1][d], xd, s1);
                s2 = fmaf(Wx[2][d], xd, s2);
            }
            Cr[i] = s0; Cz[i] = s1; Cnh[i] = s2;   // Cnh holds gi_n for now
        }
        // stash gi_n, run hh-part of n in Cnh
        float gin[4];
#pragma unroll
        for (int i = 0; i < 4; ++i) { gin[i] = Cnh[i]; Cnh[i] = bh0n; }

        Cr = MFMA16(aH0[0][0], W0h[0][0], Cr, 0, 0, 0);
        Cr = MFMA16(aH0[1][0], W0h[0][1], Cr, 0, 0, 0);
        Cr = MFMA16(aH0[0][1], W0h[0][0], Cr, 0, 0, 0);
        Cr = MFMA16(aH0[1][1], W0h[0][1], Cr, 0, 0, 0);
        Cr = MFMA16(aH0[0][0], W0l[0][0], Cr, 0, 0, 0);
        Cr = MFMA16(aH0[1][0], W0l[0][1], Cr, 0, 0, 0);
        Cz = MFMA16(aH0[0][0], W0h[1][0], Cz, 0, 0, 0);
        Cz = MFMA16(aH0[1][0], W0h[1][1], Cz, 0, 0, 0);
        Cz = MFMA16(aH0[0][1], W0h[1][0], Cz, 0, 0, 0);
        Cz = MFMA16(aH0[1][1], W0h[1][1], Cz, 0, 0, 0);
        Cz = MFMA16(aH0[0][0], W0l[1][0], Cz, 0, 0, 0);
        Cz = MFMA16(aH0[1][0], W0l[1][1], Cz, 0, 0, 0);
        Cnh = MFMA16(aH0[0][0], W0h[2][0], Cnh, 0, 0, 0);
        Cnh = MFMA16(aH0[1][0], W0h[2][1], Cnh, 0, 0, 0);
        Cnh = MFMA16(aH0[0][1], W0h[2][0], Cnh, 0, 0, 0);
        Cnh = MFMA16(aH0[1][1], W0h[2][1], Cnh, 0, 0, 0);
        Cnh = MFMA16(aH0[0][0], W0l[2][0], Cnh, 0, 0, 0);
        Cnh = MFMA16(aH0[1][0], W0l[2][1], Cnh, 0, 0, 0);

        unsigned short hh[4], hl[4];
#pragma unroll
        for (int i = 0; i < 4; ++i) {
            float r = sigf(Cr[i]);
            float z = sigf(Cz[i]);
            float n = tanhf_(gin[i] + bi0n + r * Cnh[i]);
            h0f[i] = (1.f - z) * n + z * h0f[i];
            hh[i] = f2bf(h0f[i]);
            hl[i] = f2bf(h0f[i] - bf2f(hh[i]));
        }
        __syncthreads();   // B1: all h0 A-reads done
#pragma unroll
        for (int i = 0; i < 4; ++i) {
            *(unsigned short*)(ldsb + wAo[i]) = hh[i];
            *(unsigned short*)(ldsb + wAo[i] + 4096) = hl[i];
        }
        // read h1(old) here: h1 planes are written only after B2 (safe zone)
        short8v aH1[2][2];
        aH1[0][0] = LD8(bA0 + 8192);  aH1[1][0] = LD8(bA1 + 8192);
        aH1[0][1] = LD8(bA0 + 12288); aH1[1][1] = LD8(bA1 + 12288);
        __syncthreads();   // B2: h0' visible

        // ===== layer 1 =====
        short8v aN[2][2];
        aN[0][0] = LD8(bA0);        aN[1][0] = LD8(bA1);
        aN[0][1] = LD8(bA0 + 4096); aN[1][1] = LD8(bA1 + 4096);

        f32x4 Dr, Dz, Dni, Dnh;
#pragma unroll
        for (int i = 0; i < 4; ++i) {
            Dr[i] = brz1_r; Dz[i] = brz1_z; Dni[i] = bi1n; Dnh[i] = bh1n;
        }
        Dr = MFMA16(aN[0][0], V1h[0][0], Dr, 0, 0, 0);
        Dr = MFMA16(aN[1][0], V1h[0][1], Dr, 0, 0, 0);
        Dr = MFMA16(aN[0][1], V1h[0][0], Dr, 0, 0, 0);
        Dr = MFMA16(aN[1][1], V1h[0][1], Dr, 0, 0, 0);
        Dr = MFMA16(aN[0][0], V1l[0][0], Dr, 0, 0, 0);
        Dr = MFMA16(aN[1][0], V1l[0][1], Dr, 0, 0, 0);
        Dr = MFMA16(aH1[0][0], U1h[0][0], Dr, 0, 0, 0);
        Dr = MFMA16(aH1[1][0], U1h[0][1], Dr, 0, 0, 0);
        Dr = MFMA16(aH1[0][1], U1h[0][0], Dr, 0, 0, 0);
        Dr = MFMA16(aH1[1][1], U1h[0][1], Dr, 0, 0, 0);
        Dr = MFMA16(aH1[0][0], U1l[0][0], Dr, 0, 0, 0);
        Dr = MFMA16(aH1[1][0], U1l[0][1], Dr, 0, 0, 0);

        Dz = MFMA16(aN[0][0], V1h[1][0], Dz, 0, 0, 0);
        Dz = MFMA16(aN[1][0], V1h[1][1], Dz, 0, 0, 0);
        Dz = MFMA16(aN[0][1], V1h[1][0], Dz, 0, 0, 0);
        Dz = MFMA16(aN[1][1], V1h[1][1], Dz, 0, 0, 0);
        Dz = MFMA16(aN[0][0], V1l[1][0], Dz, 0, 0, 0);
        Dz = MFMA16(aN[1][0], V1l[1][1], Dz, 0, 0, 0);
        Dz = MFMA16(aH1[0][0], U1h[1][0], Dz, 0, 0, 0);
        Dz = MFMA16(aH1[1][0], U1h[1][1], Dz, 0, 0, 0);
        Dz = MFMA16(aH1[0][1], U1h[1][0], Dz, 0, 0, 0);
        Dz = MFMA16(aH1[1][1], U1h[1][1], Dz, 0, 0, 0);
        Dz = MFMA16(aH1[0][0], U1l[1][0], Dz, 0, 0, 0);
        Dz = MFMA16(aH1[1][0], U1l[1][1], Dz, 0, 0, 0);

        Dni = MFMA16(aN[0][0], V1h[2][0], Dni, 0, 0, 0);
        Dni = MFMA16(aN[1][0], V1h[2][1], Dni, 0, 0, 0);
        Dni = MFMA16(aN[0][1], V1h[2][0], Dni, 0, 0, 0);
        Dni = MFMA16(aN[1][1], V1h[2][1], Dni, 0, 0, 0);
        Dni = MFMA16(aN[0][0], V1l[2][0], Dni, 0, 0, 0);
        Dni = MFMA16(aN[1][0], V1l[2][1], Dni, 0, 0, 0);
        Dnh = MFMA16(aH1[0][0], U1h[2][0], Dnh, 0, 0, 0);
        Dnh = MFMA16(aH1[1][0], U1h[2][1], Dnh, 0, 0, 0);
        Dnh = MFMA16(aH1[0][1], U1h[2][0], Dnh, 0, 0, 0);
        Dnh = MFMA16(aH1[1][1], U1h[2][1], Dnh, 0, 0, 0);
        Dnh = MFMA16(aH1[0][0], U1l[2][0], Dnh, 0, 0, 0);
        Dnh = MFMA16(aH1[1][0], U1l[2][1], Dnh, 0, 0, 0);

#pragma unroll
        for (int i = 0; i < 4; ++i) {
            float r = sigf(Dr[i]);
            float z = sigf(Dz[i]);
            float n = tanhf_(Dni[i] + r * Dnh[i]);
            h1f[i] = (1.f - z) * n + z * h1f[i];
            unsigned short hhi = f2bf(h1f[i]);
            *(unsigned short*)(ldsb + wAo[i] + 8192) = hhi;
            *(unsigned short*)(ldsb + wAo[i] + 12288) = f2bf(h1f[i] - bf2f(hhi));
        }
        __syncthreads();   // B3: h1' visible; next step safe
    }

#pragma unroll
    for (int i = 0; i < 4; ++i)
        hidden[(size_t)(n0 + mt * 16 + kb * 4 + i) * 64 + u_m] = h1f[i];
#undef LD8
}

// ---------------------------------------------------------------------------
// K2: t = hidden @ tW.T + tb ; s1 = t@a1 ; s2 = t@a2 ; + exp branch tables.
// ---------------------------------------------------------------------------
__global__ __launch_bounds__(256)
void attn_prep(const float* __restrict__ hidden, const float* __restrict__ tW,
               const float* __restrict__ tb, const float* __restrict__ a,
               float* __restrict__ s1, float* __restrict__ s2,
               float* __restrict__ E1p, float* __restrict__ E1n,
               float* __restrict__ E2p, float* __restrict__ E2n)
{
    __shared__ float WT[64 * 65];
    __shared__ float hrow[4][64];
    int tid = threadIdx.x, c = tid & 63, rw = tid >> 6;
    for (int i = tid; i < 4096; i += 256) {
        int cc = i >> 6, u = i & 63;          // tW[cc][u], coalesced read
        WT[u * 65 + cc] = tW[i];
    }
    int row = blockIdx.x * 4 + rw;
    hrow[rw][c] = hidden[(size_t)row * 64 + c];
    __syncthreads();
    float tc = tb[c];
    for (int u = 0; u < 64; ++u) tc += WT[u * 65 + c] * hrow[rw][u];
    float p1 = tc * a[c], p2 = tc * a[64 + c];
#pragma unroll
    for (int o = 32; o; o >>= 1) { p1 += __shfl_xor(p1, o); p2 += __shfl_xor(p2, o); }
    if (c == 0) {
        s1[row] = p1; s2[row] = p2;
        E1p[row] = expf(p1); E1n[row] = expf(0.01f * p1);
        E2p[row] = expf(p2); E2n[row] = expf(0.01f * p2);
    }
}

// ---------------------------------------------------------------------------
// K3: frag-native transposed planes: hiTf[j>>3][c][8] (hi and lo).
// ---------------------------------------------------------------------------
__global__ __launch_bounds__(256)
void transposeHbf(const float* __restrict__ hidden,
                  unsigned short* __restrict__ hiTh, unsigned short* __restrict__ hiTl)
{
    __shared__ float tile[64][65];
    int b = blockIdx.x, tid = threadIdx.x;
    for (int i = tid; i < 4096; i += 256) {
        int r = i >> 6, c = i & 63;
        tile[c][r] = hidden[(size_t)(b * 64 + r) * 64 + c];
    }
    __syncthreads();
    int c = tid & 63, seg = tid >> 6;      // 16 j's per (c,seg)
    unsigned short oh[16], ol[16];
#pragma unroll
    for (int k = 0; k < 16; ++k) {
        float v = tile[c][seg * 16 + k];
        unsigned short h = f2bf(v);
        oh[k] = h; ol[k] = f2bf(v - bf2f(h));
    }
    int jb = b * 8 + seg * 2;              // j>>3 of first 8-chunk
    size_t b0 = ((size_t)jb * 64 + c) * 8;
    size_t b1 = ((size_t)(jb + 1) * 64 + c) * 8;
    *(short8v*)(hiTh + b0) = *(const short8v*)(oh);
    *(short8v*)(hiTh + b1) = *(const short8v*)(oh + 8);
    *(short8v*)(hiTl + b0) = *(const short8v*)(ol);
    *(short8v*)(hiTl + b1) = *(const short8v*)(ol + 8);
}

// ---------------------------------------------------------------------------
// K4: flash attention (rank-1 branch decomposition) + FUSED fc/out epilogue.
// 512 blocks x 4 waves; block = 16 att-rows, wave = j-quarter.
// Epilogue: h2 rows -> LDS, then fc+leaky+out dot in-block (kills fc_out
// kernel, h2 round-trip, and 2048 redundant fcW stagings).
// ---------------------------------------------------------------------------
__global__ __launch_bounds__(256)
void flash_attn(const float* __restrict__ s1, const float* __restrict__ s2,
                const float* __restrict__ E1p, const float* __restrict__ E1n,
                const float* __restrict__ E2p, const float* __restrict__ E2n,
                const unsigned short* __restrict__ hiTh,
                const unsigned short* __restrict__ hiTl,
                const float* __restrict__ hidden,
                const float* __restrict__ fcW, const float* __restrict__ fcb,
                const float* __restrict__ outW, const float* __restrict__ outb,
                float* __restrict__ out)
{
    __shared__ float comb[4][64][17];
    __shared__ float fcWT[64 * 65];
    __shared__ float h2s[16 * 65];
    const int tid = threadIdx.x;
    const int l = tid & 63, w = tid >> 6;     // w = j-quarter
    const int l15 = l & 15, kb = l >> 4;
    const int i0 = blockIdx.x * 16;

    // stage fcW transposed+padded (coalesced read, conflict-free write)
    for (int i = tid; i < 4096; i += 256) {
        int cc = i >> 6, u = i & 63;
        fcWT[u * 65 + cc] = fcW[i];
    }

    const float s2i  = s2[i0 + l15];
    const float E2pv = E2p[i0 + l15];
    const float E2nv = E2n[i0 + l15];

    f32x4 C[4];
#pragma unroll
    for (int ct = 0; ct < 4; ++ct)
#pragma unroll
        for (int r = 0; r < 4; ++r) C[ct][r] = 0.f;
    float den = 0.f;

#pragma unroll 2
    for (int it = 0; it < 64; ++it) {
        const int jk = w * 2048 + it * 32 + kb * 8;
        const int jb = w * 256 + it * 4 + kb;          // j>>3
        float4 s1a = *(const float4*)(s1 + jk);
        float4 s1b = *(const float4*)(s1 + jk + 4);
        float4 p1a = *(const float4*)(E1p + jk);
        float4 p1b = *(const float4*)(E1p + jk + 4);
        float4 n1a = *(const float4*)(E1n + jk);
        float4 n1b = *(const float4*)(E1n + jk + 4);

        short8v Bh[4], Bl[4];
#pragma unroll
        for (int ct = 0; ct < 4; ++ct) {
            size_t off = ((size_t)jb * 64 + ct * 16 + l15) * 8;
            Bh[ct] = *(const short8v*)(hiTh + off);
            Bl[ct] = *(const short8v*)(hiTl + off);
        }

        unsigned short ah[8], al[8];
#define MK(e, sv, pv, nv)                                            \
        {                                                            \
            float s = s2i + (sv);                                    \
            bool cpos = s > 0.f;                                     \
            float w1 = cpos ? (pv) : (nv);                           \
            float w2 = cpos ? E2pv : E2nv;                           \
            float ev = w1 * w2;                                      \
            den += ev;                                               \
            unsigned short hx = f2bf(ev);                            \
            ah[e] = hx; al[e] = f2bf(ev - bf2f(hx));                 \
        }
        MK(0, s1a.x, p1a.x, n1a.x) MK(1, s1a.y, p1a.y, n1a.y)
        MK(2, s1a.z, p1a.z, n1a.z) MK(3, s1a.w, p1a.w, n1a.w)
        MK(4, s1b.x, p1b.x, n1b.x) MK(5, s1b.y, p1b.y, n1b.y)
        MK(6, s1b.z, p1b.z, n1b.z) MK(7, s1b.w, p1b.w, n1b.w)
#undef MK
        short8v Ah = { (short)ah[0], (short)ah[1], (short)ah[2], (short)ah[3],
                       (short)ah[4], (short)ah[5], (short)ah[6], (short)ah[7] };
        short8v Al = { (short)al[0], (short)al[1], (short)al[2], (short)al[3],
                       (short)al[4], (short)al[5], (short)al[6], (short)al[7] };

#pragma unroll
        for (int ct = 0; ct < 4; ++ct) {
            C[ct] = MFMA16(Ah, Bh[ct], C[ct], 0, 0, 0);
            C[ct] = MFMA16(Al, Bh[ct], C[ct], 0, 0, 0);
            C[ct] = MFMA16(Ah, Bl[ct], C[ct], 0, 0, 0);
        }
    }

    den += __shfl_xor(den, 16);
    den += __shfl_xor(den, 32);

#pragma unroll
    for (int ct = 0; ct < 4; ++ct)
#pragma unroll
        for (int r = 0; r < 4; ++r) comb[w][l][ct * 4 + r] = C[ct][r];
    comb[w][l][16] = den;
    __syncthreads();

    if (w == 0) {
        float den_t = comb[0][l][16] + comb[1][l][16] + comb[2][l][16] + comb[3][l][16];
#pragma unroll
        for (int ct = 0; ct < 4; ++ct) {
#pragma unroll
            for (int r = 0; r < 4; ++r) {
                int rr = kb * 4 + r;
                float num = comb[0][l][ct * 4 + r] + comb[1][l][ct * 4 + r]
                          + comb[2][l][ct * 4 + r] + comb[3][l][ct * 4 + r];
                float dv = __shfl(den_t, rr);
                size_t oidx = (size_t)(i0 + rr) * 64 + ct * 16 + l15;
                h2s[rr * 65 + ct * 16 + l15] = num / dv + hidden[oidx];
            }
        }
    }
    __syncthreads();

    // fused fc + leaky + out: wave w handles rows w*4..w*4+3; lane = channel
#pragma unroll
    for (int rr = 0; rr < 4; ++rr) {
        int row = w * 4 + rr;
        float y = fcb[l];
        for (int u = 0; u < 64; ++u)
            y = fmaf(fcWT[u * 65 + l], h2s[row * 65 + u], y);
        y = y > 0.f ? y : 0.01f * y;
        float o = y * outW[l];
#pragma unroll
        for (int sft = 32; sft; sft >>= 1) o += __shfl_xor(o, sft);
        if (l == 0) out[i0 + row] = o + outb[0];
    }
}

extern "C" void kernel_launch(void* const* d_in, const int* in_sizes, int n_in,
                              void* d_out, int out_size, void* d_ws, size_t ws_size,
                              hipStream_t stream)
{
    const float* x     = (const float*)d_in[0];
    const float* Wih0  = (const float*)d_in[1];
    const float* Whh0  = (const float*)d_in[2];
    const float* bih0  = (const float*)d_in[3];
    const float* bhh0  = (const float*)d_in[4];
    const float* Wih1  = (const float*)d_in[5];
    const float* Whh1  = (const float*)d_in[6];
    const float* bih1  = (const float*)d_in[7];
    const float* bhh1  = (const float*)d_in[8];
    const float* tW    = (const float*)d_in[9];
    const float* tb    = (const float*)d_in[10];
    const float* a     = (const float*)d_in[11];
    const float* fcW   = (const float*)d_in[12];
    const float* fcb   = (const float*)d_in[13];
    const float* outW  = (const float*)d_in[14];
    const float* outb  = (const float*)d_in[15];

    float* ws      = (float*)d_ws;
    float* hidden  = ws;                          // 8192*64        (524288)
    float* s1      = hidden + 524288;             // 8192
    float* s2      = s1 + 8192;
    float* E1p     = s2 + 8192;
    float* E1n     = E1p + 8192;
    float* E2p     = E1n + 8192;
    float* E2n     = E2p + 8192;                  // ends at 573440 floats
    unsigned short* hiTh = (unsigned short*)(ws + 573440);   // 8192*64 u16
    unsigned short* hiTl = hiTh + 524288;                    // 8192*64 u16

    gru_fused<<<256, 512, 0, stream>>>(x, Wih0, Whh0, bih0, bhh0,
                                       Wih1, Whh1, bih1, bhh1, hidden);
    attn_prep<<<2048, 256, 0, stream>>>(hidden, tW, tb, a, s1, s2,
                                        E1p, E1n, E2p, E2n);
    transposeHbf<<<128, 256, 0, stream>>>(hidden, hiTh, hiTl);
    flash_attn<<<512, 256, 0, stream>>>(s1, s2, E1p, E1n, E2p, E2n,
                                        hiTh, hiTl, hidden,
                                        fcW, fcb, outW, outb, (float*)d_out);
}

// Round 10
// 454.159 us; speedup vs baseline: 1.2510x; 1.0660x over previous
//
#include <hip/hip_runtime.h>
#include <hip/hip_bf16.h>
#include <math.h>

#define TSTEPS 60
#define DIN 6

typedef __attribute__((ext_vector_type(8))) short short8v;
typedef __attribute__((ext_vector_type(4))) float f32x4;
#define MFMA16 __builtin_amdgcn_mfma_f32_16x16x32_bf16

__device__ __forceinline__ float fast_rcp(float x) { return __builtin_amdgcn_rcpf(x); }
__device__ __forceinline__ float sigf(float x) { return fast_rcp(1.0f + __expf(-x)); }
__device__ __forceinline__ float tanhf_(float x) {
    return 1.0f - 2.0f * fast_rcp(__expf(2.0f * x) + 1.0f);
}
__device__ __forceinline__ unsigned short f2bf(float f) {   // RTN-even
    unsigned u = __float_as_uint(f);
    u += 0x7fff + ((u >> 16) & 1);
    return (unsigned short)(u >> 16);
}
__device__ __forceinline__ float bf2f(unsigned short s) {
    return __uint_as_float(((unsigned)s) << 16);
}
// load 8 consecutive fp32 -> split-bf16 hi/lo frags
__device__ __forceinline__ void ld_split(const float* p, short8v& hi, short8v& lo) {
    float4 a = *(const float4*)p, b = *(const float4*)(p + 4);
    float v[8] = {a.x, a.y, a.z, a.w, b.x, b.y, b.z, b.w};
    short h8[8], l8[8];
#pragma unroll
    for (int e = 0; e < 8; ++e) {
        unsigned short h = f2bf(v[e]);
        h8[e] = (short)h; l8[e] = (short)f2bf(v[e] - bf2f(h));
    }
    hi = *(short8v*)h8; lo = *(short8v*)l8;
}

// ---------------------------------------------------------------------------
// K1: fused 2-layer GRU, 60 steps, MFMA split-bf16 (hi+lo, 3-term) matmuls.
// ROUND-10 RESTRUCTURE: 256-thread blocks (4 waves, 16 rows), grid 512,
// amdgpu_waves_per_eu(2,2) -> explicit 256-VGPR budget, 2 blocks/CU.
// Weight B-frags in REGISTERS (36 frags = 144 VGPR; total demand ~250).
// Rounds 7/9: 8-wave blocks got a 128-VGPR budget -> ~120-reg scratch spill
// (WRITE 61MB, FETCH 172MB). This shape makes the 256 budget legal.
// LDS = 8 KB h planes only (h0hi|h0lo|h1hi|h1lo @ 0/2048/4096/6144).
// ---------------------------------------------------------------------------
__global__ __launch_bounds__(256)
__attribute__((amdgpu_waves_per_eu(2, 2)))
void gru_fused(const float* __restrict__ x,
               const float* __restrict__ Wih0, const float* __restrict__ Whh0,
               const float* __restrict__ bih0, const float* __restrict__ bhh0,
               const float* __restrict__ Wih1, const float* __restrict__ Whh1,
               const float* __restrict__ bih1, const float* __restrict__ bhh1,
               float* __restrict__ hidden)
{
    __shared__ char ldsb[8192];

    const int tid = threadIdx.x;
    const int l   = tid & 63;
    const int ur  = tid >> 6;        // wave = unit-range 0..3
    const int l15 = l & 15;
    const int kb  = l >> 4;
    const int u_m = ur * 16 + l15;   // my unit column
    const int n0  = blockIdx.x * 16;

    for (int i = tid; i < 2048; i += 256) *(unsigned*)(ldsb + i * 4) = 0u;

    // ---- weight fragments -> registers (one-time) ----
    short8v W0h[3][2], W0l[3][2];    // Whh0  [gate][kt]
    short8v V1h[3][2], V1l[3][2];    // Wih1
    short8v U1h[3][2], U1l[3][2];    // Whh1
#pragma unroll
    for (int g = 0; g < 3; ++g)
#pragma unroll
        for (int kt = 0; kt < 2; ++kt) {
            int off = (g * 64 + u_m) * 64 + kt * 32 + kb * 8;
            ld_split(Whh0 + off, W0h[g][kt], W0l[g][kt]);
            ld_split(Wih1 + off, V1h[g][kt], V1l[g][kt]);
            ld_split(Whh1 + off, U1h[g][kt], U1l[g][kt]);
        }

    float brz0_r = bih0[u_m] + bhh0[u_m];
    float brz0_z = bih0[64 + u_m] + bhh0[64 + u_m];
    float bi0n = bih0[128 + u_m], bh0n = bhh0[128 + u_m];
    float brz1_r = bih1[u_m] + bhh1[u_m];
    float brz1_z = bih1[64 + u_m] + bhh1[64 + u_m];
    float bi1n = bih1[128 + u_m], bh1n = bhh1[128 + u_m];

    float Wx[3][DIN];
#pragma unroll
    for (int g = 0; g < 3; ++g)
#pragma unroll
        for (int d = 0; d < DIN; ++d) Wx[g][d] = Wih0[(g * 64 + u_m) * DIN + d];

    const int bA0 = l15 * 128 + ((kb ^ (l15 & 7)) << 4);
    const int bA1 = bA0 ^ 64;
    int wAo[4];
#pragma unroll
    for (int i = 0; i < 4; ++i) {
        int r = kb * 4 + i;
        wAo[i] = r * 128 + (((u_m >> 3) ^ (r & 7)) << 4) + (u_m & 7) * 2;
    }
    const float* xp[4];
#pragma unroll
    for (int i = 0; i < 4; ++i)
        xp[i] = x + (size_t)(n0 + kb * 4 + i) * (DIN * TSTEPS);

    float h0f[4] = {0.f, 0.f, 0.f, 0.f};
    float h1f[4] = {0.f, 0.f, 0.f, 0.f};

    __syncthreads();

#define LD8(o) (*(const short8v*)(ldsb + (o)))

#pragma unroll 1
    for (int t = 0; t < TSTEPS; ++t) {
        // A-frags of h0(old):  [kt][hi/lo]
        short8v aH0[2][2];
        aH0[0][0] = LD8(bA0);        aH0[1][0] = LD8(bA1);
        aH0[0][1] = LD8(bA0 + 2048); aH0[1][1] = LD8(bA1 + 2048);

        // accumulators init with bias + x-part
        f32x4 Cr, Cz, Cnh;
#pragma unroll
        for (int i = 0; i < 4; ++i) {
            float s0 = brz0_r, s1 = brz0_z, s2 = 0.f;
#pragma unroll
            for (int d = 0; d < DIN; ++d) {
                float xd = xp[i][d * TSTEPS + t];
                s0 = fmaf(Wx[0][d], xd, s0);
                s1 = fmaf(Wx[1][d], xd, s1);
                s2 = fmaf(Wx[2][d], xd, s2);
            }
            Cr[i] = s0; Cz[i] = s1; Cnh[i] = s2;   // Cnh holds gi_n for now
        }
        float gin[4];
#pragma unroll
        for (int i = 0; i < 4; ++i) { gin[i] = Cnh[i]; Cnh[i] = bh0n; }

        Cr = MFMA16(aH0[0][0], W0h[0][0], Cr, 0, 0, 0);
        Cr = MFMA16(aH0[1][0], W0h[0][1], Cr, 0, 0, 0);
        Cr = MFMA16(aH0[0][1], W0h[0][0], Cr, 0, 0, 0);
        Cr = MFMA16(aH0[1][1], W0h[0][1], Cr, 0, 0, 0);
        Cr = MFMA16(aH0[0][0], W0l[0][0], Cr, 0, 0, 0);
        Cr = MFMA16(aH0[1][0], W0l[0][1], Cr, 0, 0, 0);
        Cz = MFMA16(aH0[0][0], W0h[1][0], Cz, 0, 0, 0);
        Cz = MFMA16(aH0[1][0], W0h[1][1], Cz, 0, 0, 0);
        Cz = MFMA16(aH0[0][1], W0h[1][0], Cz, 0, 0, 0);
        Cz = MFMA16(aH0[1][1], W0h[1][1], Cz, 0, 0, 0);
        Cz = MFMA16(aH0[0][0], W0l[1][0], Cz, 0, 0, 0);
        Cz = MFMA16(aH0[1][0], W0l[1][1], Cz, 0, 0, 0);
        Cnh = MFMA16(aH0[0][0], W0h[2][0], Cnh, 0, 0, 0);
        Cnh = MFMA16(aH0[1][0], W0h[2][1], Cnh, 0, 0, 0);
        Cnh = MFMA16(aH0[0][1], W0h[2][0], Cnh, 0, 0, 0);
        Cnh = MFMA16(aH0[1][1], W0h[2][1], Cnh, 0, 0, 0);
        Cnh = MFMA16(aH0[0][0], W0l[2][0], Cnh, 0, 0, 0);
        Cnh = MFMA16(aH0[1][0], W0l[2][1], Cnh, 0, 0, 0);

        unsigned short hh[4], hl[4];
#pragma unroll
        for (int i = 0; i < 4; ++i) {
            float r = sigf(Cr[i]);
            float z = sigf(Cz[i]);
            float n = tanhf_(gin[i] + bi0n + r * Cnh[i]);
            h0f[i] = (1.f - z) * n + z * h0f[i];
            hh[i] = f2bf(h0f[i]);
            hl[i] = f2bf(h0f[i] - bf2f(hh[i]));
        }
        __syncthreads();   // B1: all h0 A-reads done
#pragma unroll
        for (int i = 0; i < 4; ++i) {
            *(unsigned short*)(ldsb + wAo[i]) = hh[i];
            *(unsigned short*)(ldsb + wAo[i] + 2048) = hl[i];
        }
        // read h1(old) here: h1 planes are written only after B2 (safe zone)
        short8v aH1[2][2];
        aH1[0][0] = LD8(bA0 + 4096); aH1[1][0] = LD8(bA1 + 4096);
        aH1[0][1] = LD8(bA0 + 6144); aH1[1][1] = LD8(bA1 + 6144);
        __syncthreads();   // B2: h0' visible

        // ===== layer 1 =====
        short8v aN[2][2];
        aN[0][0] = LD8(bA0);        aN[1][0] = LD8(bA1);
        aN[0][1] = LD8(bA0 + 2048); aN[1][1] = LD8(bA1 + 2048);

        f32x4 Dr, Dz, Dni, Dnh;
#pragma unroll
        for (int i = 0; i < 4; ++i) {
            Dr[i] = brz1_r; Dz[i] = brz1_z; Dni[i] = bi1n; Dnh[i] = bh1n;
        }
        Dr = MFMA16(aN[0][0], V1h[0][0], Dr, 0, 0, 0);
        Dr = MFMA16(aN[1][0], V1h[0][1], Dr, 0, 0, 0);
        Dr = MFMA16(aN[0][1], V1h[0][0], Dr, 0, 0, 0);
        Dr = MFMA16(aN[1][1], V1h[0][1], Dr, 0, 0, 0);
        Dr = MFMA16(aN[0][0], V1l[0][0], Dr, 0, 0, 0);
        Dr = MFMA16(aN[1][0], V1l[0][1], Dr, 0, 0, 0);
        Dr = MFMA16(aH1[0][0], U1h[0][0], Dr, 0, 0, 0);
        Dr = MFMA16(aH1[1][0], U1h[0][1], Dr, 0, 0, 0);
        Dr = MFMA16(aH1[0][1], U1h[0][0], Dr, 0, 0, 0);
        Dr = MFMA16(aH1[1][1], U1h[0][1], Dr, 0, 0, 0);
        Dr = MFMA16(aH1[0][0], U1l[0][0], Dr, 0, 0, 0);
        Dr = MFMA16(aH1[1][0], U1l[0][1], Dr, 0, 0, 0);

        Dz = MFMA16(aN[0][0], V1h[1][0], Dz, 0, 0, 0);
        Dz = MFMA16(aN[1][0], V1h[1][1], Dz, 0, 0, 0);
        Dz = MFMA16(aN[0][1], V1h[1][0], Dz, 0, 0, 0);
        Dz = MFMA16(aN[1][1], V1h[1][1], Dz, 0, 0, 0);
        Dz = MFMA16(aN[0][0], V1l[1][0], Dz, 0, 0, 0);
        Dz = MFMA16(aN[1][0], V1l[1][1], Dz, 0, 0, 0);
        Dz = MFMA16(aH1[0][0], U1h[1][0], Dz, 0, 0, 0);
        Dz = MFMA16(aH1[1][0], U1h[1][1], Dz, 0, 0, 0);
        Dz = MFMA16(aH1[0][1], U1h[1][0], Dz, 0, 0, 0);
        Dz = MFMA16(aH1[1][1], U1h[1][1], Dz, 0, 0, 0);
        Dz = MFMA16(aH1[0][0], U1l[1][0], Dz, 0, 0, 0);
        Dz = MFMA16(aH1[1][0], U1l[1][1], Dz, 0, 0, 0);

        Dni = MFMA16(aN[0][0], V1h[2][0], Dni, 0, 0, 0);
        Dni = MFMA16(aN[1][0], V1h[2][1], Dni, 0, 0, 0);
        Dni = MFMA16(aN[0][1], V1h[2][0], Dni, 0, 0, 0);
        Dni = MFMA16(aN[1][1], V1h[2][1], Dni, 0, 0, 0);
        Dni = MFMA16(aN[0][0], V1l[2][0], Dni, 0, 0, 0);
        Dni = MFMA16(aN[1][0], V1l[2][1], Dni, 0, 0, 0);
        Dnh = MFMA16(aH1[0][0], U1h[2][0], Dnh, 0, 0, 0);
        Dnh = MFMA16(aH1[1][0], U1h[2][1], Dnh, 0, 0, 0);
        Dnh = MFMA16(aH1[0][1], U1h[2][0], Dnh, 0, 0, 0);
        Dnh = MFMA16(aH1[1][1], U1h[2][1], Dnh, 0, 0, 0);
        Dnh = MFMA16(aH1[0][0], U1l[2][0], Dnh, 0, 0, 0);
        Dnh = MFMA16(aH1[1][0], U1l[2][1], Dnh, 0, 0, 0);

#pragma unroll
        for (int i = 0; i < 4; ++i) {
            float r = sigf(Dr[i]);
            float z = sigf(Dz[i]);
            float n = tanhf_(Dni[i] + r * Dnh[i]);
            h1f[i] = (1.f - z) * n + z * h1f[i];
            unsigned short hhi = f2bf(h1f[i]);
            *(unsigned short*)(ldsb + wAo[i] + 4096) = hhi;
            *(unsigned short*)(ldsb + wAo[i] + 6144) = f2bf(h1f[i] - bf2f(hhi));
        }
        __syncthreads();   // B3: h1' visible; next step safe
    }

#pragma unroll
    for (int i = 0; i < 4; ++i)
        hidden[(size_t)(n0 + kb * 4 + i) * 64 + u_m] = h1f[i];
#undef LD8
}

// ---------------------------------------------------------------------------
// K2: t = hidden @ tW.T + tb ; s1 = t@a1 ; s2 = t@a2 ; + exp branch tables.
// ---------------------------------------------------------------------------
__global__ __launch_bounds__(256)
void attn_prep(const float* __restrict__ hidden, const float* __restrict__ tW,
               const float* __restrict__ tb, const float* __restrict__ a,
               float* __restrict__ s1, float* __restrict__ s2,
               float* __restrict__ E1p, float* __restrict__ E1n,
               float* __restrict__ E2p, float* __restrict__ E2n)
{
    __shared__ float WT[64 * 65];
    __shared__ float hrow[4][64];
    int tid = threadIdx.x, c = tid & 63, rw = tid >> 6;
    for (int i = tid; i < 4096; i += 256) {
        int cc = i >> 6, u = i & 63;          // tW[cc][u], coalesced read
        WT[u * 65 + cc] = tW[i];
    }
    int row = blockIdx.x * 4 + rw;
    hrow[rw][c] = hidden[(size_t)row * 64 + c];
    __syncthreads();
    float tc = tb[c];
    for (int u = 0; u < 64; ++u) tc += WT[u * 65 + c] * hrow[rw][u];
    float p1 = tc * a[c], p2 = tc * a[64 + c];
#pragma unroll
    for (int o = 32; o; o >>= 1) { p1 += __shfl_xor(p1, o); p2 += __shfl_xor(p2, o); }
    if (c == 0) {
        s1[row] = p1; s2[row] = p2;
        E1p[row] = expf(p1); E1n[row] = expf(0.01f * p1);
        E2p[row] = expf(p2); E2n[row] = expf(0.01f * p2);
    }
}

// ---------------------------------------------------------------------------
// K3: frag-native transposed planes: hiTf[j>>3][c][8] (hi and lo).
// ---------------------------------------------------------------------------
__global__ __launch_bounds__(256)
void transposeHbf(const float* __restrict__ hidden,
                  unsigned short* __restrict__ hiTh, unsigned short* __restrict__ hiTl)
{
    __shared__ float tile[64][65];
    int b = blockIdx.x, tid = threadIdx.x;
    for (int i = tid; i < 4096; i += 256) {
        int r = i >> 6, c = i & 63;
        tile[c][r] = hidden[(size_t)(b * 64 + r) * 64 + c];
    }
    __syncthreads();
    int c = tid & 63, seg = tid >> 6;      // 16 j's per (c,seg)
    unsigned short oh[16], ol[16];
#pragma unroll
    for (int k = 0; k < 16; ++k) {
        float v = tile[c][seg * 16 + k];
        unsigned short h = f2bf(v);
        oh[k] = h; ol[k] = f2bf(v - bf2f(h));
    }
    int jb = b * 8 + seg * 2;              // j>>3 of first 8-chunk
    size_t b0 = ((size_t)jb * 64 + c) * 8;
    size_t b1 = ((size_t)(jb + 1) * 64 + c) * 8;
    *(short8v*)(hiTh + b0) = *(const short8v*)(oh);
    *(short8v*)(hiTh + b1) = *(const short8v*)(oh + 8);
    *(short8v*)(hiTl + b0) = *(const short8v*)(ol);
    *(short8v*)(hiTl + b1) = *(const short8v*)(ol + 8);
}

// ---------------------------------------------------------------------------
// K4: flash attention (rank-1 branch decomposition) + FUSED fc/out epilogue.
// 512 blocks x 4 waves; block = 16 att-rows, wave = j-quarter.
// ---------------------------------------------------------------------------
__global__ __launch_bounds__(256)
void flash_attn(const float* __restrict__ s1, const float* __restrict__ s2,
                const float* __restrict__ E1p, const float* __restrict__ E1n,
                const float* __restrict__ E2p, const float* __restrict__ E2n,
                const unsigned short* __restrict__ hiTh,
                const unsigned short* __restrict__ hiTl,
                const float* __restrict__ hidden,
                const float* __restrict__ fcW, const float* __restrict__ fcb,
                const float* __restrict__ outW, const float* __restrict__ outb,
                float* __restrict__ out)
{
    __shared__ float comb[4][64][17];
    __shared__ float fcWT[64 * 65];
    __shared__ float h2s[16 * 65];
    const int tid = threadIdx.x;
    const int l = tid & 63, w = tid >> 6;     // w = j-quarter
    const int l15 = l & 15, kb = l >> 4;
    const int i0 = blockIdx.x * 16;

    // stage fcW transposed+padded (coalesced read, conflict-free write)
    for (int i = tid; i < 4096; i += 256) {
        int cc = i >> 6, u = i & 63;
        fcWT[u * 65 + cc] = fcW[i];
    }

    const float s2i  = s2[i0 + l15];
    const float E2pv = E2p[i0 + l15];
    const float E2nv = E2n[i0 + l15];

    f32x4 C[4];
#pragma unroll
    for (int ct = 0; ct < 4; ++ct)
#pragma unroll
        for (int r = 0; r < 4; ++r) C[ct][r] = 0.f;
    float den = 0.f;

#pragma unroll 2
    for (int it = 0; it < 64; ++it) {
        const int jk = w * 2048 + it * 32 + kb * 8;
        const int jb = w * 256 + it * 4 + kb;          // j>>3
        float4 s1a = *(const float4*)(s1 + jk);
        float4 s1b = *(const float4*)(s1 + jk + 4);
        float4 p1a = *(const float4*)(E1p + jk);
        float4 p1b = *(const float4*)(E1p + jk + 4);
        float4 n1a = *(const float4*)(E1n + jk);
        float4 n1b = *(const float4*)(E1n + jk + 4);

        short8v Bh[4], Bl[4];
#pragma unroll
        for (int ct = 0; ct < 4; ++ct) {
            size_t off = ((size_t)jb * 64 + ct * 16 + l15) * 8;
            Bh[ct] = *(const short8v*)(hiTh + off);
            Bl[ct] = *(const short8v*)(hiTl + off);
        }

        unsigned short ah[8], al[8];
#define MK(e, sv, pv, nv)                                            \
        {                                                            \
            float s = s2i + (sv);                                    \
            bool cpos = s > 0.f;                                     \
            float w1 = cpos ? (pv) : (nv);                           \
            float w2 = cpos ? E2pv : E2nv;                           \
            float ev = w1 * w2;                                      \
            den += ev;                                               \
            unsigned short hx = f2bf(ev);                            \
            ah[e] = hx; al[e] = f2bf(ev - bf2f(hx));                 \
        }
        MK(0, s1a.x, p1a.x, n1a.x) MK(1, s1a.y, p1a.y, n1a.y)
        MK(2, s1a.z, p1a.z, n1a.z) MK(3, s1a.w, p1a.w, n1a.w)
        MK(4, s1b.x, p1b.x, n1b.x) MK(5, s1b.y, p1b.y, n1b.y)
        MK(6, s1b.z, p1b.z, n1b.z) MK(7, s1b.w, p1b.w, n1b.w)
#undef MK
        short8v Ah = { (short)ah[0], (short)ah[1], (short)ah[2], (short)ah[3],
                       (short)ah[4], (short)ah[5], (short)ah[6], (short)ah[7] };
        short8v Al = { (short)al[0], (short)al[1], (short)al[2], (short)al[3],
                       (short)al[4], (short)al[5], (short)al[6], (short)al[7] };

#pragma unroll
        for (int ct = 0; ct < 4; ++ct) {
            C[ct] = MFMA16(Ah, Bh[ct], C[ct], 0, 0, 0);
            C[ct] = MFMA16(Al, Bh[ct], C[ct], 0, 0, 0);
            C[ct] = MFMA16(Ah, Bl[ct], C[ct], 0, 0, 0);
        }
    }

    den += __shfl_xor(den, 16);
    den += __shfl_xor(den, 32);

#pragma unroll
    for (int ct = 0; ct < 4; ++ct)
#pragma unroll
        for (int r = 0; r < 4; ++r) comb[w][l][ct * 4 + r] = C[ct][r];
    comb[w][l][16] = den;
    __syncthreads();

    if (w == 0) {
        float den_t = comb[0][l][16] + comb[1][l][16] + comb[2][l][16] + comb[3][l][16];
#pragma unroll
        for (int ct = 0; ct < 4; ++ct) {
#pragma unroll
            for (int r = 0; r < 4; ++r) {
                int rr = kb * 4 + r;
                float num = comb[0][l][ct * 4 + r] + comb[1][l][ct * 4 + r]
                          + comb[2][l][ct * 4 + r] + comb[3][l][ct * 4 + r];
                float dv = __shfl(den_t, rr);
                size_t oidx = (size_t)(i0 + rr) * 64 + ct * 16 + l15;
                h2s[rr * 65 + ct * 16 + l15] = num / dv + hidden[oidx];
            }
        }
    }
    __syncthreads();

    // fused fc + leaky + out: wave w handles rows w*4..w*4+3; lane = channel
#pragma unroll
    for (int rr = 0; rr < 4; ++rr) {
        int row = w * 4 + rr;
        float y = fcb[l];
        for (int u = 0; u < 64; ++u)
            y = fmaf(fcWT[u * 65 + l], h2s[row * 65 + u], y);
        y = y > 0.f ? y : 0.01f * y;
        float o = y * outW[l];
#pragma unroll
        for (int sft = 32; sft; sft >>= 1) o += __shfl_xor(o, sft);
        if (l == 0) out[i0 + row] = o + outb[0];
    }
}

extern "C" void kernel_launch(void* const* d_in, const int* in_sizes, int n_in,
                              void* d_out, int out_size, void* d_ws, size_t ws_size,
                              hipStream_t stream)
{
    const float* x     = (const float*)d_in[0];
    const float* Wih0  = (const float*)d_in[1];
    const float* Whh0  = (const float*)d_in[2];
    const float* bih0  = (const float*)d_in[3];
    const float* bhh0  = (const float*)d_in[4];
    const float* Wih1  = (const float*)d_in[5];
    const float* Whh1  = (const float*)d_in[6];
    const float* bih1  = (const float*)d_in[7];
    const float* bhh1  = (const float*)d_in[8];
    const float* tW    = (const float*)d_in[9];
    const float* tb    = (const float*)d_in[10];
    const float* a     = (const float*)d_in[11];
    const float* fcW   = (const float*)d_in[12];
    const float* fcb   = (const float*)d_in[13];
    const float* outW  = (const float*)d_in[14];
    const float* outb  = (const float*)d_in[15];

    float* ws      = (float*)d_ws;
    float* hidden  = ws;                          // 8192*64        (524288)
    float* s1      = hidden + 524288;             // 8192
    float* s2      = s1 + 8192;
    float* E1p     = s2 + 8192;
    float* E1n     = E1p + 8192;
    float* E2p     = E1n + 8192;
    float* E2n     = E2p + 8192;                  // ends at 573440 floats
    unsigned short* hiTh = (unsigned short*)(ws + 573440);   // 8192*64 u16
    unsigned short* hiTl = hiTh + 524288;                    // 8192*64 u16

    gru_fused<<<512, 256, 0, stream>>>(x, Wih0, Whh0, bih0, bhh0,
                                       Wih1, Whh1, bih1, bhh1, hidden);
    attn_prep<<<2048, 256, 0, stream>>>(hidden, tW, tb, a, s1, s2,
                                        E1p, E1n, E2p, E2n);
    transposeHbf<<<128, 256, 0, stream>>>(hidden, hiTh, hiTl);
    flash_attn<<<512, 256, 0, stream>>>(s1, s2, E1p, E1n, E2p, E2n,
                                        hiTh, hiTl, hidden,
                                        fcW, fcb, outW, outb, (float*)d_out);
}